// Round 1
// 347.309 us; speedup vs baseline: 1.1033x; 1.1033x over previous
//
#include <hip/hip_runtime.h>

#define N_NODES 100000
#define N_EDGES 1600000
#define IN_DIM 128
#define HID 64
#define NB 782               // ceil(100000 / 128) buckets of 128 nodes
#define NBLK_GEMM 782        // ceil(100000 / 128) gemm blocks (128 rows each)
#define NGROUP 25000         // N_NODES / 4 agg groups

typedef __attribute__((ext_vector_type(8))) _Float16 h8v;
typedef __attribute__((ext_vector_type(4))) float f4v;

struct Args {
  const float* x; const int* ei;
  const float* Wp; const float* bp;
  const float* W1; const float* b1;
  const float* W2; const float* b2;
  const float* W3; const float* b3;
  float* out;
  _Float16* bufA16; _Float16* hw16;
  int* pairs; int* csr; int* offs; float* dinv;
  int* bsz; int* bboff; int* bcur;
  _Float16* WpH; _Float16* WpL; _Float16* W1H; _Float16* W1L;
  _Float16* W2H; _Float16* W2L; _Float16* W3H; _Float16* W3L;
};

// ---------------- weight prep: split fp32 W[K][64] -> transposed half hi/lo ----
__device__ __forceinline__ void d_split(const float* __restrict__ W,
                                        _Float16* __restrict__ hi,
                                        _Float16* __restrict__ lo, int K, int i) {
  int k = i >> 6, n = i & 63;
  float v = W[i];
  _Float16 h = (_Float16)v;
  float r = v - (float)h;
  hi[n * K + k] = h;
  lo[n * K + k] = (_Float16)r;
}

__global__ __launch_bounds__(256) void f_prep(Args a) {
  int blk = blockIdx.x, t = threadIdx.x;
  if (blk < 32) d_split(a.Wp, a.WpH, a.WpL, IN_DIM, blk * 256 + t);
  else if (blk < 48) d_split(a.W1, a.W1H, a.W1L, HID, (blk - 32) * 256 + t);
  else if (blk < 64) d_split(a.W2, a.W2H, a.W2L, HID, (blk - 48) * 256 + t);
  else d_split(a.W3, a.W3H, a.W3L, HID, (blk - 64) * 256 + t);
}

// ---------------- bucket histogram ----------------
__global__ __launch_bounds__(256) void f_bhist(Args a) {
  __shared__ int cnt[NB];
  int t = threadIdx.x;
  for (int i = t; i < NB; i += 256) cnt[i] = 0;
  __syncthreads();
  int e0 = blockIdx.x * 8192, e1 = min(e0 + 8192, N_EDGES);
  for (int e = e0 + t; e < e1; e += 256)
    atomicAdd(&cnt[a.ei[N_EDGES + e] >> 7], 1);
  __syncthreads();
  for (int i = t; i < NB; i += 256)
    if (cnt[i]) atomicAdd(&a.bsz[i], cnt[i]);
}

// ---------------- bucket exclusive scan (1 block, 256 thr x 4 slots) ----------
__global__ __launch_bounds__(256) void f_bscan(Args a) {
  __shared__ int sm[256];
  int t = threadIdx.x;
  int c[4];
  int idx0 = t * 4;
#pragma unroll
  for (int j = 0; j < 4; ++j) c[j] = (idx0 + j < NB) ? a.bsz[idx0 + j] : 0;
  int tsum = c[0] + c[1] + c[2] + c[3];
  int val = tsum;
  sm[t] = val;
  __syncthreads();
  for (int off = 1; off < 256; off <<= 1) {
    int u = (t >= off) ? sm[t - off] : 0;
    __syncthreads();
    val += u;
    sm[t] = val;
    __syncthreads();
  }
  int excl = val - tsum;
#pragma unroll
  for (int j = 0; j < 4; ++j) {
    int idx = idx0 + j;
    if (idx < NB) { a.bboff[idx] = excl; a.bcur[idx] = excl; }
    excl += c[j];
  }
  if (t == 255) a.bboff[NB] = val;  // == N_EDGES
}

// ---------------- partition edges into buckets; pack (dlocal<<17 | src) --------
__global__ __launch_bounds__(256) void f_partition(Args a) {
  __shared__ int cnt[NB];
  __shared__ int base[NB];
  int t = threadIdx.x;
  for (int i = t; i < NB; i += 256) cnt[i] = 0;
  __syncthreads();
  int e0 = blockIdx.x * 8192, e1 = min(e0 + 8192, N_EDGES);
  for (int e = e0 + t; e < e1; e += 256)
    atomicAdd(&cnt[a.ei[N_EDGES + e] >> 7], 1);
  __syncthreads();
  for (int i = t; i < NB; i += 256) {
    int c = cnt[i];
    base[i] = c ? atomicAdd(&a.bcur[i], c) : 0;
    cnt[i] = 0;
  }
  __syncthreads();
  for (int e = e0 + t; e < e1; e += 256) {
    int s = a.ei[e];
    int d = a.ei[N_EDGES + e];
    int b = d >> 7;
    int r = atomicAdd(&cnt[b], 1);
    a.pairs[base[b] + r] = ((d & 127) << 17) | s;
  }
}

// ---------------- per-bucket degrees + offs + dinv + CSR scatter ---------------
__global__ __launch_bounds__(256) void f_csrdeg(Args a) {
  __shared__ int ldeg[128];
  __shared__ int sc[128];
  __shared__ int lcur[128];
  int t = threadIdx.x;
  int b = blockIdx.x;
  int node0 = b << 7;
  int nloc = min(128, N_NODES - node0);
  int beg = a.bboff[b], end = a.bboff[b + 1];
  if (t < 128) ldeg[t] = 0;
  __syncthreads();
  for (int i = beg + t; i < end; i += 256)
    atomicAdd(&ldeg[(a.pairs[i] >> 17) & 127], 1);
  __syncthreads();
  int dv = (t < 128) ? ldeg[t] : 0;
  if (t < 128) sc[t] = dv;
  __syncthreads();
  for (int off = 1; off < 128; off <<= 1) {
    int u = (t >= off && t < 128) ? sc[t - off] : 0;
    __syncthreads();
    if (t < 128) sc[t] += u;
    __syncthreads();
  }
  if (t < nloc) {
    int o = beg + sc[t] - dv;
    a.offs[node0 + t] = o;
    lcur[t] = o;
    a.dinv[node0 + t] = rsqrtf((float)dv + 1.0f);
  }
  if (b == NB - 1 && t == 0) a.offs[N_NODES] = N_EDGES;
  __syncthreads();
  for (int i = beg + t; i < end; i += 256) {
    int p = a.pairs[i];
    int pos = atomicAdd(&lcur[(p >> 17) & 127], 1);
    a.csr[pos] = p & 131071;
  }
}

// ---- pre GEMM v2: LDS-staged swizzled weights, 2 frags/wave, dbuf x prefetch ----
// block = 256 thr = 4 waves; each wave does 2 fragments of 16 rows -> 128 rows/block
__global__ __launch_bounds__(256) void f_gemm_pre(Args a) {
  __shared__ _Float16 sW[2 * 64 * IN_DIM];  // hi | lo halves, XOR-swizzled (32 KB)
  int t = threadIdx.x;
  int wave = t >> 6, lane = t & 63, fi = lane & 15, quad = lane >> 4;
  int r0 = blockIdx.x * 128 + wave * 32;

  // prefetch x for fragment 0 (registers) while weights stage
  f4v xb0[8], xb1[8];
  {
    int row = r0 + fi; if (row >= N_NODES) row = N_NODES - 1;
    const float* xp = a.x + (size_t)row * IN_DIM + quad * 8;
#pragma unroll
    for (int j = 0; j < 4; ++j) {
      xb0[2 * j]     = *(const f4v*)(xp + j * 32);
      xb0[2 * j + 1] = *(const f4v*)(xp + j * 32 + 4);
    }
  }
  // stage 32 KB of weights into LDS. chunk = 16B. swizzle: byte ^= (n&7)<<4
  // (row stride 256B => unswizzled ds_read_b128 is a 16-way bank conflict)
#pragma unroll
  for (int i = 0; i < 8; ++i) {
    int c = i * 256 + t;               // 0..2047
    int h = c >> 10;                   // 0 = hi, 1 = lo
    int c2 = c & 1023;                 // chunk within half
    int n = c2 >> 4;                   // output-col row (16 chunks per row)
    const _Float16* src = (h ? a.WpL : a.WpH) + c2 * 8;
    f4v v = *(const f4v*)src;
    int off = (h << 14) | ((c2 * 16) ^ ((n & 7) << 4));
    *(f4v*)((char*)sW + off) = v;
  }
  __syncthreads();

  float bv[4];
#pragma unroll
  for (int ct = 0; ct < 4; ++ct) bv[ct] = a.bp[ct * 16 + fi];

#pragma unroll
  for (int f = 0; f < 2; ++f) {
    f4v* xcur = (f & 1) ? xb1 : xb0;
    f4v* xnxt = (f & 1) ? xb0 : xb1;
    if (f < 1) {  // prefetch next fragment while computing this one
      int row = r0 + 16 + fi; if (row >= N_NODES) row = N_NODES - 1;
      const float* xp = a.x + (size_t)row * IN_DIM + quad * 8;
#pragma unroll
      for (int j = 0; j < 4; ++j) {
        xnxt[2 * j]     = *(const f4v*)(xp + j * 32);
        xnxt[2 * j + 1] = *(const f4v*)(xp + j * 32 + 4);
      }
    }
    f4v acc[4];
#pragma unroll
    for (int ct = 0; ct < 4; ++ct) acc[ct] = (f4v){0.f, 0.f, 0.f, 0.f};
#pragma unroll
    for (int k0i = 0; k0i < 4; ++k0i) {
      h8v ah, al;
#pragma unroll
      for (int j = 0; j < 4; ++j) {
        float v0 = xcur[2 * k0i][j], v1 = xcur[2 * k0i + 1][j];
        _Float16 h0 = (_Float16)v0, h1 = (_Float16)v1;
        ah[j] = h0;     al[j] = (_Float16)(v0 - (float)h0);
        ah[4 + j] = h1; al[4 + j] = (_Float16)(v1 - (float)h1);
      }
#pragma unroll
      for (int ct = 0; ct < 4; ++ct) {
        int n = ct * 16 + fi;
        int bo = ((n * IN_DIM + k0i * 32 + quad * 8) * 2) ^ ((n & 7) << 4);
        h8v bh = *(const h8v*)((const char*)sW + bo);
        h8v bl = *(const h8v*)((const char*)sW + 16384 + bo);
        acc[ct] = __builtin_amdgcn_mfma_f32_16x16x32_f16(ah, bh, acc[ct], 0, 0, 0);
        acc[ct] = __builtin_amdgcn_mfma_f32_16x16x32_f16(al, bh, acc[ct], 0, 0, 0);
        acc[ct] = __builtin_amdgcn_mfma_f32_16x16x32_f16(ah, bl, acc[ct], 0, 0, 0);
      }
    }
    int ro = r0 + f * 16;
#pragma unroll
    for (int ct = 0; ct < 4; ++ct) {
#pragma unroll
      for (int j = 0; j < 4; ++j) {
        int orow = ro + quad * 4 + j;
        if (orow < N_NODES)
          a.bufA16[(size_t)orow * HID + ct * 16 + fi] = (_Float16)(acc[ct][j] + bv[ct]);
      }
    }
  }
}

// ---- hidden GEMM v2: B entirely register-resident (64 VGPR), stream A dbuf ----
// block = 256 thr = 4 waves; each wave 2 fragments of 16 rows -> 128 rows/block
__global__ __launch_bounds__(256) void f_gemm64(Args a, const _Float16* __restrict__ Wh,
                                                const _Float16* __restrict__ Wl) {
  int t = threadIdx.x;
  int wave = t >> 6, lane = t & 63, fi = lane & 15, quad = lane >> 4;
  int r0 = blockIdx.x * 128 + wave * 32;

  // issue A fragment 0 load first (HBM), then B loads (L2-resident 16 KB)
  h8v a0[2], a1[2];
  {
    int row = r0 + fi; if (row >= N_NODES) row = N_NODES - 1;
    const _Float16* xp = a.bufA16 + (size_t)row * HID + quad * 8;
    a0[0] = *(const h8v*)xp;
    a0[1] = *(const h8v*)(xp + 32);
  }
  h8v Bh[2][4], Bl[2][4];
#pragma unroll
  for (int k0i = 0; k0i < 2; ++k0i)
#pragma unroll
    for (int ct = 0; ct < 4; ++ct) {
      size_t o = (size_t)(ct * 16 + fi) * HID + k0i * 32 + quad * 8;
      Bh[k0i][ct] = *(const h8v*)(Wh + o);
      Bl[k0i][ct] = *(const h8v*)(Wl + o);
    }

#pragma unroll
  for (int f = 0; f < 2; ++f) {
    h8v* av = (f & 1) ? a1 : a0;
    h8v* nx = (f & 1) ? a0 : a1;
    if (f < 1) {
      int row = r0 + 16 + fi; if (row >= N_NODES) row = N_NODES - 1;
      const _Float16* xp = a.bufA16 + (size_t)row * HID + quad * 8;
      nx[0] = *(const h8v*)xp;
      nx[1] = *(const h8v*)(xp + 32);
    }
    f4v acc[4];
#pragma unroll
    for (int ct = 0; ct < 4; ++ct) acc[ct] = (f4v){0.f, 0.f, 0.f, 0.f};
#pragma unroll
    for (int k0i = 0; k0i < 2; ++k0i)
#pragma unroll
      for (int ct = 0; ct < 4; ++ct) {
        acc[ct] = __builtin_amdgcn_mfma_f32_16x16x32_f16(av[k0i], Bh[k0i][ct], acc[ct], 0, 0, 0);
        acc[ct] = __builtin_amdgcn_mfma_f32_16x16x32_f16(av[k0i], Bl[k0i][ct], acc[ct], 0, 0, 0);
      }
    int ro = r0 + f * 16;
#pragma unroll
    for (int ct = 0; ct < 4; ++ct)
#pragma unroll
      for (int j = 0; j < 4; ++j) {
        int orow = ro + quad * 4 + j;
        if (orow < N_NODES)
          a.hw16[(size_t)orow * HID + ct * 16 + fi] = (_Float16)acc[ct][j];
      }
  }
}

// ---- aggregation: wave per node, oct-parallel, 4-deep (32 gathers in flight) ----
// MODE 0: bias+relu -> fp16 bufA16    MODE 1: bias + L2 normalize -> fp32 out
template <int MODE>
__device__ __forceinline__ void d_agg(int grp, const _Float16* __restrict__ hw,
                                      const int* __restrict__ offs,
                                      const int* __restrict__ csr,
                                      const float* __restrict__ dinv,
                                      const float* __restrict__ bias,
                                      _Float16* __restrict__ out16,
                                      float* __restrict__ out32) {
  int node = grp * 4 + (threadIdx.x >> 6);
  int lane = threadIdx.x & 63;
  int oct = lane >> 3;
  int fi = lane & 7;
  float di = dinv[node];
  int beg = offs[node];
  int end = offs[node + 1];

  float acc[8];
#pragma unroll
  for (int c = 0; c < 8; ++c) acc[c] = 0.f;

  if (oct == 0) {  // self-loop term
    h8v hv = *(const h8v*)(hw + (size_t)node * HID + fi * 8);
    float w = di * di;
#pragma unroll
    for (int c = 0; c < 8; ++c) acc[c] += (float)hv[c] * w;
  }
  for (int e0 = beg + oct; e0 < end; e0 += 32) {
    int ss[4];
    float ww[4];
#pragma unroll
    for (int j = 0; j < 4; ++j) {
      int e = e0 + 8 * j;
      bool v = e < end;
      int s = csr[v ? e : beg];
      ss[j] = v ? s : node;
      ww[j] = v ? di : 0.0f;
    }
#pragma unroll
    for (int j = 0; j < 4; ++j) ww[j] *= dinv[ss[j]];
    h8v hv[4];
#pragma unroll
    for (int j = 0; j < 4; ++j)
      hv[j] = *(const h8v*)(hw + (size_t)ss[j] * HID + fi * 8);
#pragma unroll
    for (int j = 0; j < 4; ++j)
#pragma unroll
      for (int c = 0; c < 8; ++c) acc[c] += (float)hv[j][c] * ww[j];
  }
#pragma unroll
  for (int c = 0; c < 8; ++c) {
    float v = acc[c];
    v += __shfl_xor(v, 8);
    v += __shfl_xor(v, 16);
    v += __shfl_xor(v, 32);
    acc[c] = v;
  }
  if (oct == 0) {
#pragma unroll
    for (int c = 0; c < 8; ++c) acc[c] += bias[fi * 8 + c];
    if (MODE == 0) {
      h8v o;
#pragma unroll
      for (int c = 0; c < 8; ++c) o[c] = (_Float16)fmaxf(acc[c], 0.f);
      *(h8v*)(out16 + (size_t)node * HID + fi * 8) = o;
    } else {
      float ss = 0.f;
#pragma unroll
      for (int c = 0; c < 8; ++c) ss += acc[c] * acc[c];
      ss += __shfl_xor(ss, 1);
      ss += __shfl_xor(ss, 2);
      ss += __shfl_xor(ss, 4);
      float sc = 1.0f / fmaxf(sqrtf(ss), 1e-12f);
      f4v o0 = {acc[0] * sc, acc[1] * sc, acc[2] * sc, acc[3] * sc};
      f4v o1 = {acc[4] * sc, acc[5] * sc, acc[6] * sc, acc[7] * sc};
      *(f4v*)(out32 + (size_t)node * HID + fi * 8) = o0;
      *(f4v*)(out32 + (size_t)node * HID + fi * 8 + 4) = o1;
    }
  }
}

__global__ __launch_bounds__(256) void f_agg_relu(Args a, const float* bias) {
  d_agg<0>(blockIdx.x, a.hw16, a.offs, a.csr, a.dinv, bias, a.bufA16, nullptr);
}

__global__ __launch_bounds__(256) void f_agg_norm(Args a) {
  d_agg<1>(blockIdx.x, a.hw16, a.offs, a.csr, a.dinv, a.b3, nullptr, a.out);
}

extern "C" void kernel_launch(void* const* d_in, const int* in_sizes, int n_in,
                              void* d_out, int out_size, void* d_ws, size_t ws_size,
                              hipStream_t stream) {
  char* ws = (char*)d_ws;
  Args a;
  a.x  = (const float*)d_in[0];
  a.ei = (const int*)d_in[1];
  a.Wp = (const float*)d_in[2];  a.bp = (const float*)d_in[3];
  a.W1 = (const float*)d_in[4];  a.b1 = (const float*)d_in[5];
  a.W2 = (const float*)d_in[6];  a.b2 = (const float*)d_in[7];
  a.W3 = (const float*)d_in[8];  a.b3 = (const float*)d_in[9];
  a.out  = (float*)d_out;
  a.bufA16 = (_Float16*)(ws + 0);             // 12.8 MB fp16 activations
  a.hw16   = (_Float16*)(ws + 12800000);      // 12.8 MB fp16 gemm out
  a.pairs  = (int*)(ws + 25600000);           // 6.4 MB packed (dlocal<<17|src)
  a.csr    = (int*)(ws + 32000000);           // 6.4 MB
  a.offs   = (int*)(ws + 38400000);           // (N+1) ints
  a.dinv   = (float*)(ws + 38800016);         // 400 KB
  a.bsz    = (int*)(ws + 39200016);           // NB ints
  a.bboff  = (int*)(ws + 39203152);           // NB+1 ints
  a.bcur   = (int*)(ws + 39206288);           // NB ints
  a.WpH = (_Float16*)(ws + 39210000);         // 16 KB
  a.WpL = (_Float16*)(ws + 39226384);
  a.W1H = (_Float16*)(ws + 39242768);         // 8 KB each
  a.W1L = (_Float16*)(ws + 39250960);
  a.W2H = (_Float16*)(ws + 39259152);
  a.W2L = (_Float16*)(ws + 39267344);
  a.W3H = (_Float16*)(ws + 39275536);
  a.W3L = (_Float16*)(ws + 39283728);

  (void)hipMemsetAsync(a.bsz, 0, NB * sizeof(int), stream);
  f_prep<<<80, 256, 0, stream>>>(a);
  f_bhist<<<196, 256, 0, stream>>>(a);
  f_bscan<<<1, 256, 0, stream>>>(a);
  f_partition<<<196, 256, 0, stream>>>(a);
  f_csrdeg<<<NB, 256, 0, stream>>>(a);
  f_gemm_pre<<<NBLK_GEMM, 256, 0, stream>>>(a);
  f_gemm64<<<NBLK_GEMM, 256, 0, stream>>>(a, a.W1H, a.W1L);
  f_agg_relu<<<NGROUP, 256, 0, stream>>>(a, a.b1);
  f_gemm64<<<NBLK_GEMM, 256, 0, stream>>>(a, a.W2H, a.W2L);
  f_agg_relu<<<NGROUP, 256, 0, stream>>>(a, a.b2);
  f_gemm64<<<NBLK_GEMM, 256, 0, stream>>>(a, a.W3H, a.W3L);
  f_agg_norm<<<NGROUP, 256, 0, stream>>>(a);
}